// Round 2
// baseline (921.851 us; speedup 1.0000x reference)
//
#include <hip/hip_runtime.h>
#include <hip/hip_bf16.h>

// Problem: B=64, N=577, E=1024, H=16, D=64.
// out = softmax((xWq^T)(xWk^T)^T / 8) (xWv^T), head-split.
// ws layout: Q,K,V bf16 in [B][H][N][D], each 75,628,544 bytes (total 226.9 MB).

typedef __attribute__((ext_vector_type(8))) short s16x8;
typedef __attribute__((ext_vector_type(4))) float f32x4;

#define MFMA16(a, b, c) __builtin_amdgcn_mfma_f32_16x16x32_bf16((a), (b), (c), 0, 0, 0)

__device__ __forceinline__ short f2bf(float f) {
    unsigned u = __builtin_bit_cast(unsigned, f);
    u += 0x7FFFu + ((u >> 16) & 1u);   // round-to-nearest-even
    return (short)(u >> 16);
}

// ---------------------------------------------------------------------------
// QKV projection GEMM: out[m,o] = sum_k x[m,k] * W[o,k]   (NT gemm, K=1024)
// 128x128 tile, BK=32, 4 waves (each 64x64 = 4x4 fragments of 16x16x32 bf16).
// f32 inputs converted to bf16 during reg-staging into LDS.
// Epilogue writes bf16 directly into [B][H][N][D] layout.
// ---------------------------------------------------------------------------
__global__ __launch_bounds__(256) void qkv_gemm(
    const float* __restrict__ x,
    const float* __restrict__ Wq,
    const float* __restrict__ Wk,
    const float* __restrict__ Wv,
    short* __restrict__ Qb,
    short* __restrict__ Kb,
    short* __restrict__ Vb)
{
    constexpr int M = 64 * 577;   // 36928
    constexpr int K = 1024;
    __shared__ short As[128 * 32];
    __shared__ short Bs[128 * 32];

    const int t    = threadIdx.x;
    const int lane = t & 63;
    const int w    = t >> 6;
    const int wr   = w >> 1, wc = w & 1;
    const int g    = lane >> 4, ml = lane & 15;
    const int tileM = blockIdx.y * 128;
    const int tileN = blockIdx.x * 128;
    const float* W = (blockIdx.z == 0) ? Wq : (blockIdx.z == 1) ? Wk : Wv;
    short* Ob      = (blockIdx.z == 0) ? Qb : (blockIdx.z == 1) ? Kb : Vb;

    f32x4 acc[4][4] = {};

    for (int k0 = 0; k0 < K; k0 += 32) {
        // Stage A and B tiles (128 rows x 32 k) as bf16. Slot s (16B) = row s>>2, k8 (s&3)*8.
        #pragma unroll
        for (int p = 0; p < 2; ++p) {
            int s   = t + p * 256;
            int row = s >> 2;
            int kk  = (s & 3) * 8;
            int ar  = tileM + row; if (ar > M - 1) ar = M - 1;
            const float* ga = x + (size_t)ar * K + (k0 + kk);
            float4 a0 = *reinterpret_cast<const float4*>(ga);
            float4 a1 = *reinterpret_cast<const float4*>(ga + 4);
            s16x8 av;
            av[0]=f2bf(a0.x); av[1]=f2bf(a0.y); av[2]=f2bf(a0.z); av[3]=f2bf(a0.w);
            av[4]=f2bf(a1.x); av[5]=f2bf(a1.y); av[6]=f2bf(a1.z); av[7]=f2bf(a1.w);
            *reinterpret_cast<s16x8*>(&As[row * 32 + kk]) = av;

            const float* gb = W + (size_t)(tileN + row) * K + (k0 + kk);
            float4 b0 = *reinterpret_cast<const float4*>(gb);
            float4 b1 = *reinterpret_cast<const float4*>(gb + 4);
            s16x8 bv;
            bv[0]=f2bf(b0.x); bv[1]=f2bf(b0.y); bv[2]=f2bf(b0.z); bv[3]=f2bf(b0.w);
            bv[4]=f2bf(b1.x); bv[5]=f2bf(b1.y); bv[6]=f2bf(b1.z); bv[7]=f2bf(b1.w);
            *reinterpret_cast<s16x8*>(&Bs[row * 32 + kk]) = bv;
        }
        __syncthreads();

        s16x8 af[4], bf8[4];
        #pragma unroll
        for (int i = 0; i < 4; ++i) {
            af[i]  = *reinterpret_cast<const s16x8*>(&As[(wr*64 + i*16 + ml) * 32 + g*8]);
            bf8[i] = *reinterpret_cast<const s16x8*>(&Bs[(wc*64 + i*16 + ml) * 32 + g*8]);
        }
        #pragma unroll
        for (int mi = 0; mi < 4; ++mi)
            #pragma unroll
            for (int ni = 0; ni < 4; ++ni)
                acc[mi][ni] = MFMA16(af[mi], bf8[ni], acc[mi][ni]);
        __syncthreads();
    }

    // C layout: row = (lane>>4)*4 + reg, col = lane&15.
    // Store into [B][H][N][D]: out row r -> (b = r/577, n = r%577); col c -> (h = c>>6, d = c&63)
    #pragma unroll
    for (int mi = 0; mi < 4; ++mi) {
        #pragma unroll
        for (int j = 0; j < 4; ++j) {
            int row = tileM + wr*64 + mi*16 + g*4 + j;
            if (row < M) {
                int b = row / 577;
                int n = row - b * 577;
                #pragma unroll
                for (int ni = 0; ni < 4; ++ni) {
                    int col = tileN + wc*64 + ni*16 + ml;
                    int h = col >> 6, d = col & 63;
                    Ob[(((size_t)(b * 16 + h)) * 577 + n) * 64 + d] = f2bf(acc[mi][ni][j]);
                }
            }
        }
    }
}

// ---------------------------------------------------------------------------
// Flash attention: grid (10 q-tiles, 1024 bh). 4 waves x 16 q-rows, KV tiles of 64.
// K in LDS XOR-swizzled ([64][64] bf16, slot ^= row&7); V transposed into [64][72];
// P through padded per-wave LDS [16][72]. Online softmax per lane (4 rows).
// ---------------------------------------------------------------------------
__global__ __launch_bounds__(256) void attn_fwd(
    const short* __restrict__ Qb,
    const short* __restrict__ Kb,
    const short* __restrict__ Vb,
    float* __restrict__ out)
{
    constexpr int N = 577;
    __shared__ short Ks[64 * 64];
    __shared__ short VTs[64 * 72];
    __shared__ short Ps[4][16 * 72];

    const int t    = threadIdx.x;
    const int lane = t & 63;
    const int w    = t >> 6;
    const int g    = lane >> 4, m = lane & 15;
    const int qt   = blockIdx.x;
    const int bh   = blockIdx.y;
    const size_t slab = (size_t)bh * (N * 64);

    // Q fragments (A operand: row = lane&15, k = 8*(lane>>4)+i), rows clamped for tail
    int qr = qt * 64 + w * 16 + m; if (qr > N - 1) qr = N - 1;
    const s16x8 qf0 = *reinterpret_cast<const s16x8*>(Qb + slab + (size_t)qr * 64 + g * 8);
    const s16x8 qf1 = *reinterpret_cast<const s16x8*>(Qb + slab + (size_t)qr * 64 + 32 + g * 8);

    float m_run[4] = {-1e30f, -1e30f, -1e30f, -1e30f};
    float l_run[4] = {0.f, 0.f, 0.f, 0.f};
    f32x4 o_acc[4] = {};

    for (int kv0 = 0; kv0 < N; kv0 += 64) {
        {   // stage K (swizzled) and V^T; rows clamped, OOB keys masked later
            int row  = t >> 2;
            int krow = kv0 + row; if (krow > N - 1) krow = N - 1;
            const short* gk = Kb + slab + (size_t)krow * 64;
            #pragma unroll
            for (int p = 0; p < 2; ++p) {
                int sl = (t & 3) * 2 + p;
                s16x8 kvv = *reinterpret_cast<const s16x8*>(gk + sl * 8);
                *reinterpret_cast<s16x8*>(&Ks[row * 64 + ((sl ^ (row & 7)) * 8)]) = kvv;
            }
            const short* gv = Vb + slab + (size_t)krow * 64;
            #pragma unroll
            for (int p = 0; p < 2; ++p) {
                int d0 = (t & 3) * 16 + p * 8;
                s16x8 vv = *reinterpret_cast<const s16x8*>(gv + d0);
                #pragma unroll
                for (int j = 0; j < 8; ++j) VTs[(d0 + j) * 72 + row] = vv[j];
            }
        }
        __syncthreads();

        // S = Q K^T  (per wave: 16 q-rows x 64 keys, 8 MFMAs)
        f32x4 sacc[4] = {};
        #pragma unroll
        for (int kb = 0; kb < 4; ++kb) {
            int kr = kb * 16 + m;
            s16x8 b0 = *reinterpret_cast<const s16x8*>(&Ks[kr * 64 + ((g       ^ (kr & 7)) * 8)]);
            sacc[kb] = MFMA16(qf0, b0, sacc[kb]);
            s16x8 b1 = *reinterpret_cast<const s16x8*>(&Ks[kr * 64 + (((4 + g) ^ (kr & 7)) * 8)]);
            sacc[kb] = MFMA16(qf1, b1, sacc[kb]);
        }

        // online softmax; lane holds rows g*4+i, key = kv0 + kb*16 + m
        float ss[4][4];
        #pragma unroll
        for (int kb = 0; kb < 4; ++kb) {
            bool valid = (kv0 + kb * 16 + m) < N;
            #pragma unroll
            for (int i = 0; i < 4; ++i)
                ss[kb][i] = valid ? sacc[kb][i] * 0.125f : -1e30f;
        }
        short* Pw = Ps[w];
        #pragma unroll
        for (int i = 0; i < 4; ++i) {
            float tm = fmaxf(fmaxf(ss[0][i], ss[1][i]), fmaxf(ss[2][i], ss[3][i]));
            tm = fmaxf(tm, __shfl_xor(tm, 1));
            tm = fmaxf(tm, __shfl_xor(tm, 2));
            tm = fmaxf(tm, __shfl_xor(tm, 4));
            tm = fmaxf(tm, __shfl_xor(tm, 8));
            float mn   = fmaxf(m_run[i], tm);
            float corr = __expf(m_run[i] - mn);
            m_run[i] = mn;
            float psum = 0.f;
            #pragma unroll
            for (int kb = 0; kb < 4; ++kb) {
                float p = __expf(ss[kb][i] - mn);
                psum += p;
                Pw[(g * 4 + i) * 72 + kb * 16 + m] = f2bf(p);
            }
            psum += __shfl_xor(psum, 1);
            psum += __shfl_xor(psum, 2);
            psum += __shfl_xor(psum, 4);
            psum += __shfl_xor(psum, 8);
            l_run[i] = l_run[i] * corr + psum;
            #pragma unroll
            for (int db = 0; db < 4; ++db) o_acc[db][i] *= corr;
        }
        __syncthreads();   // P visible (and K reads done)

        // O += P V  (8 MFMAs; A = P rows lane&15; B = V^T, col = d)
        #pragma unroll
        for (int ks = 0; ks < 2; ++ks) {
            s16x8 pa = *reinterpret_cast<const s16x8*>(&Pw[m * 72 + ks * 32 + g * 8]);
            #pragma unroll
            for (int db = 0; db < 4; ++db) {
                s16x8 vb = *reinterpret_cast<const s16x8*>(&VTs[(db * 16 + m) * 72 + ks * 32 + g * 8]);
                o_acc[db] = MFMA16(pa, vb, o_acc[db]);
            }
        }
        __syncthreads();   // V^T reads done before next stage
    }

    // epilogue: out[b, n, h*64+d] f32
    const int b = bh >> 4, h = bh & 15;
    #pragma unroll
    for (int i = 0; i < 4; ++i) {
        int q = qt * 64 + w * 16 + g * 4 + i;
        if (q < N) {
            float inv = 1.0f / l_run[i];
            size_t o = ((size_t)b * 577 + q) * 1024 + (size_t)h * 64;
            #pragma unroll
            for (int db = 0; db < 4; ++db)
                out[o + db * 16 + m] = o_acc[db][i] * inv;
        }
    }
}

extern "C" void kernel_launch(void* const* d_in, const int* in_sizes, int n_in,
                              void* d_out, int out_size, void* d_ws, size_t ws_size,
                              hipStream_t stream) {
    const float* x  = (const float*)d_in[0];
    const float* Wq = (const float*)d_in[1];
    const float* Wk = (const float*)d_in[2];
    const float* Wv = (const float*)d_in[3];
    float* out = (float*)d_out;

    const size_t SZ = (size_t)64 * 16 * 577 * 64 * 2;   // 75,628,544 bytes per tensor
    short* Qb = (short*)d_ws;
    short* Kb = (short*)((char*)d_ws + SZ);
    short* Vb = (short*)((char*)d_ws + 2 * SZ);

    dim3 gg(8, 289, 3);           // N-tiles x M-tiles x {Q,K,V}
    qkv_gemm<<<gg, 256, 0, stream>>>(x, Wq, Wk, Wv, Qb, Kb, Vb);

    dim3 ga(10, 1024);            // q-tiles x (B*H)
    attn_fwd<<<ga, 256, 0, stream>>>(Qb, Kb, Vb, out);
}

// Round 3
// 730.351 us; speedup vs baseline: 1.2622x; 1.2622x over previous
//
#include <hip/hip_runtime.h>
#include <hip/hip_bf16.h>

// Problem: B=64, N=577, E=1024, H=16, D=64.
// out = softmax((xWq^T)(xWk^T)^T / 8) (xWv^T), head-split.
// ws: Q,K,V bf16 [B][H][N][D], 75,628,544 B each (226.9 MB total).
// d_out doubles as scratch for bf16 x (75.6 MB) + bf16 W concat (6 MB);
// attention fully overwrites d_out at the end.

typedef __attribute__((ext_vector_type(8))) short s16x8;
typedef __attribute__((ext_vector_type(4))) float f32x4;

#define MFMA16(a, b, c) __builtin_amdgcn_mfma_f32_16x16x32_bf16((a), (b), (c), 0, 0, 0)

__device__ __forceinline__ short f2bf(float f) {
    unsigned u = __builtin_bit_cast(unsigned, f);
    u += 0x7FFFu + ((u >> 16) & 1u);   // round-to-nearest-even
    return (short)(u >> 16);
}

__device__ __forceinline__ void gload_lds16(const void* g, void* l) {
    __builtin_amdgcn_global_load_lds(
        (const __attribute__((address_space(1))) unsigned int*)g,
        (__attribute__((address_space(3))) unsigned int*)l,
        16, 0, 0);
}

// ---------------------------------------------------------------------------
// Convert x (36928x1024 f32) and Wq|Wk|Wv (each 1024x1024 f32) to bf16.
// Dest: xb = d_out[0..], Wb = d_out + 37,814,272 shorts (rows 0..3071).
// ---------------------------------------------------------------------------
__global__ __launch_bounds__(256) void convert_bf16(
    const float* __restrict__ x,
    const float* __restrict__ Wq,
    const float* __restrict__ Wk,
    const float* __restrict__ Wv,
    short* __restrict__ dst)
{
    constexpr size_t NX = 37814272u / 8u;     // x chunks of 8
    constexpr size_t NW = 1048576u / 8u;      // per-W chunks
    constexpr size_t NTOT = NX + 3u * NW;     // 5,120,000
    size_t stride = (size_t)gridDim.x * blockDim.x;
    for (size_t c = (size_t)blockIdx.x * blockDim.x + threadIdx.x; c < NTOT; c += stride) {
        const float* src;
        size_t off;
        if (c < NX) { src = x; off = c * 8; }
        else {
            size_t cw = c - NX;
            int wsel = (int)(cw / NW);
            src = (wsel == 0) ? Wq : (wsel == 1) ? Wk : Wv;
            off = (cw - (size_t)wsel * NW) * 8;
        }
        float4 a0 = *reinterpret_cast<const float4*>(src + off);
        float4 a1 = *reinterpret_cast<const float4*>(src + off + 4);
        s16x8 v;
        v[0]=f2bf(a0.x); v[1]=f2bf(a0.y); v[2]=f2bf(a0.z); v[3]=f2bf(a0.w);
        v[4]=f2bf(a1.x); v[5]=f2bf(a1.y); v[6]=f2bf(a1.z); v[7]=f2bf(a1.w);
        *reinterpret_cast<s16x8*>(dst + c * 8) = v;
    }
}

// ---------------------------------------------------------------------------
// Fused QKV GEMM (m97 structure): C[m, n] = sum_k xb[m,k] * Wb[n,k], N=3072.
// 128x128 tile, BK=32, 4 waves, global_load_lds width-16 staging, linear LDS.
// XCD-bijective swizzle, N-tile-fast for A-panel L2 reuse.
// Epilogue scatters bf16 into [B][H][N][D] for Q/K/V (z = n>>10).
// ---------------------------------------------------------------------------
__global__ __launch_bounds__(256) void qkv_gemm2(
    const short* __restrict__ xb,
    const short* __restrict__ Wb,
    short* __restrict__ Qb,
    short* __restrict__ Kb,
    short* __restrict__ Vb)
{
    constexpr int M = 36928;
    constexpr int NTILES = 24;            // 3072 / 128
    constexpr int NWG = 289 * NTILES;     // 6936, divisible by 8
    __shared__ short As[128 * 32];
    __shared__ short Bs[128 * 32];

    const int t    = threadIdx.x;
    const int lane = t & 63;
    const int w    = t >> 6;
    const int wr   = w >> 1, wc = w & 1;
    const int g    = lane >> 4, ml = lane & 15;

    // XCD swizzle (bijective: NWG % 8 == 0), n-tile fast
    int bid = blockIdx.x;
    int id  = (bid & 7) * (NWG / 8) + (bid >> 3);
    const int tileM = (id / NTILES) * 128;
    const int tileN = (id % NTILES) * 128;

    f32x4 acc[4][4] = {};

    const char* Abase = (const char*)xb;
    const char* Bbase = (const char*)Wb + (size_t)tileN * 2048;

    for (int k0 = 0; k0 < 1024; k0 += 32) {
        #pragma unroll
        for (int p = 0; p < 2; ++p) {
            int idx = p * 256 + t;
            int row = idx >> 2;
            int cb  = (idx & 3) * 16;            // col byte within 64B row
            int ar  = tileM + row; if (ar > M - 1) ar = M - 1;
            gload_lds16(Abase + (size_t)ar * 2048 + k0 * 2 + cb, (char*)As + idx * 16);
            gload_lds16(Bbase + (size_t)row * 2048 + k0 * 2 + cb, (char*)Bs + idx * 16);
        }
        __syncthreads();

        s16x8 af[4], bf8[4];
        #pragma unroll
        for (int i = 0; i < 4; ++i) {
            af[i]  = *reinterpret_cast<const s16x8*>(&As[(wr*64 + i*16 + ml) * 32 + g*8]);
            bf8[i] = *reinterpret_cast<const s16x8*>(&Bs[(wc*64 + i*16 + ml) * 32 + g*8]);
        }
        #pragma unroll
        for (int mi = 0; mi < 4; ++mi)
            #pragma unroll
            for (int ni = 0; ni < 4; ++ni)
                acc[mi][ni] = MFMA16(af[mi], bf8[ni], acc[mi][ni]);
        __syncthreads();
    }

    // z uniform per block (tileN is a multiple of 128)
    const int z = tileN >> 10;
    short* Ob = (z == 0) ? Qb : (z == 1) ? Kb : Vb;
    const int cbase = (tileN & 1023) + wc * 64;

    #pragma unroll
    for (int mi = 0; mi < 4; ++mi) {
        #pragma unroll
        for (int j = 0; j < 4; ++j) {
            int row = tileM + wr*64 + mi*16 + g*4 + j;
            if (row < M) {
                int b = row / 577;
                int n = row - b * 577;
                #pragma unroll
                for (int ni = 0; ni < 4; ++ni) {
                    int cz = cbase + ni*16 + ml;
                    int h = cz >> 6, d = cz & 63;
                    Ob[(((size_t)(b * 16 + h)) * 577 + n) * 64 + d] = f2bf(acc[mi][ni][j]);
                }
            }
        }
    }
}

// ---------------------------------------------------------------------------
// Flash attention: grid (10 q-tiles, 1024 bh). 4 waves x 16 q-rows, KV tiles of 64.
// K in LDS XOR-swizzled; V transposed into [64][72]; P via padded per-wave LDS.
// ---------------------------------------------------------------------------
__global__ __launch_bounds__(256) void attn_fwd(
    const short* __restrict__ Qb,
    const short* __restrict__ Kb,
    const short* __restrict__ Vb,
    float* __restrict__ out)
{
    constexpr int N = 577;
    __shared__ short Ks[64 * 64];
    __shared__ short VTs[64 * 72];
    __shared__ short Ps[4][16 * 72];

    const int t    = threadIdx.x;
    const int lane = t & 63;
    const int w    = t >> 6;
    const int g    = lane >> 4, m = lane & 15;
    const int qt   = blockIdx.x;
    const int bh   = blockIdx.y;
    const size_t slab = (size_t)bh * (N * 64);

    int qr = qt * 64 + w * 16 + m; if (qr > N - 1) qr = N - 1;
    const s16x8 qf0 = *reinterpret_cast<const s16x8*>(Qb + slab + (size_t)qr * 64 + g * 8);
    const s16x8 qf1 = *reinterpret_cast<const s16x8*>(Qb + slab + (size_t)qr * 64 + 32 + g * 8);

    float m_run[4] = {-1e30f, -1e30f, -1e30f, -1e30f};
    float l_run[4] = {0.f, 0.f, 0.f, 0.f};
    f32x4 o_acc[4] = {};

    for (int kv0 = 0; kv0 < N; kv0 += 64) {
        {
            int row  = t >> 2;
            int krow = kv0 + row; if (krow > N - 1) krow = N - 1;
            const short* gk = Kb + slab + (size_t)krow * 64;
            #pragma unroll
            for (int p = 0; p < 2; ++p) {
                int sl = (t & 3) * 2 + p;
                s16x8 kvv = *reinterpret_cast<const s16x8*>(gk + sl * 8);
                *reinterpret_cast<s16x8*>(&Ks[row * 64 + ((sl ^ (row & 7)) * 8)]) = kvv;
            }
            const short* gv = Vb + slab + (size_t)krow * 64;
            #pragma unroll
            for (int p = 0; p < 2; ++p) {
                int d0 = (t & 3) * 16 + p * 8;
                s16x8 vv = *reinterpret_cast<const s16x8*>(gv + d0);
                #pragma unroll
                for (int j = 0; j < 8; ++j) VTs[(d0 + j) * 72 + row] = vv[j];
            }
        }
        __syncthreads();

        f32x4 sacc[4] = {};
        #pragma unroll
        for (int kb = 0; kb < 4; ++kb) {
            int kr = kb * 16 + m;
            s16x8 b0 = *reinterpret_cast<const s16x8*>(&Ks[kr * 64 + ((g       ^ (kr & 7)) * 8)]);
            sacc[kb] = MFMA16(qf0, b0, sacc[kb]);
            s16x8 b1 = *reinterpret_cast<const s16x8*>(&Ks[kr * 64 + (((4 + g) ^ (kr & 7)) * 8)]);
            sacc[kb] = MFMA16(qf1, b1, sacc[kb]);
        }

        float ss[4][4];
        #pragma unroll
        for (int kb = 0; kb < 4; ++kb) {
            bool valid = (kv0 + kb * 16 + m) < N;
            #pragma unroll
            for (int i = 0; i < 4; ++i)
                ss[kb][i] = valid ? sacc[kb][i] * 0.125f : -1e30f;
        }
        short* Pw = Ps[w];
        #pragma unroll
        for (int i = 0; i < 4; ++i) {
            float tm = fmaxf(fmaxf(ss[0][i], ss[1][i]), fmaxf(ss[2][i], ss[3][i]));
            tm = fmaxf(tm, __shfl_xor(tm, 1));
            tm = fmaxf(tm, __shfl_xor(tm, 2));
            tm = fmaxf(tm, __shfl_xor(tm, 4));
            tm = fmaxf(tm, __shfl_xor(tm, 8));
            float mn   = fmaxf(m_run[i], tm);
            float corr = __expf(m_run[i] - mn);
            m_run[i] = mn;
            float psum = 0.f;
            #pragma unroll
            for (int kb = 0; kb < 4; ++kb) {
                float p = __expf(ss[kb][i] - mn);
                psum += p;
                Pw[(g * 4 + i) * 72 + kb * 16 + m] = f2bf(p);
            }
            psum += __shfl_xor(psum, 1);
            psum += __shfl_xor(psum, 2);
            psum += __shfl_xor(psum, 4);
            psum += __shfl_xor(psum, 8);
            l_run[i] = l_run[i] * corr + psum;
            #pragma unroll
            for (int db = 0; db < 4; ++db) o_acc[db][i] *= corr;
        }
        __syncthreads();

        #pragma unroll
        for (int ks = 0; ks < 2; ++ks) {
            s16x8 pa = *reinterpret_cast<const s16x8*>(&Pw[m * 72 + ks * 32 + g * 8]);
            #pragma unroll
            for (int db = 0; db < 4; ++db) {
                s16x8 vb = *reinterpret_cast<const s16x8*>(&VTs[(db * 16 + m) * 72 + ks * 32 + g * 8]);
                o_acc[db] = MFMA16(pa, vb, o_acc[db]);
            }
        }
        __syncthreads();
    }

    const int b = bh >> 4, h = bh & 15;
    #pragma unroll
    for (int i = 0; i < 4; ++i) {
        int q = qt * 64 + w * 16 + g * 4 + i;
        if (q < N) {
            float inv = 1.0f / l_run[i];
            size_t o = ((size_t)b * 577 + q) * 1024 + (size_t)h * 64;
            #pragma unroll
            for (int db = 0; db < 4; ++db)
                out[o + db * 16 + m] = o_acc[db][i] * inv;
        }
    }
}

extern "C" void kernel_launch(void* const* d_in, const int* in_sizes, int n_in,
                              void* d_out, int out_size, void* d_ws, size_t ws_size,
                              hipStream_t stream) {
    const float* x  = (const float*)d_in[0];
    const float* Wq = (const float*)d_in[1];
    const float* Wk = (const float*)d_in[2];
    const float* Wv = (const float*)d_in[3];
    float* out = (float*)d_out;

    const size_t SZ = (size_t)64 * 16 * 577 * 64 * 2;   // 75,628,544 B per tensor
    short* Qb = (short*)d_ws;
    short* Kb = (short*)((char*)d_ws + SZ);
    short* Vb = (short*)((char*)d_ws + 2 * SZ);

    // bf16 scratch inside d_out (fully overwritten by attn_fwd afterwards)
    short* xb = (short*)d_out;                     // 37,814,272 shorts
    short* Wb = xb + (size_t)37814272;             // 3,145,728 shorts

    convert_bf16<<<2048, 256, 0, stream>>>(x, Wq, Wk, Wv, xb);

    qkv_gemm2<<<dim3(289 * 24), 256, 0, stream>>>(xb, Wb, Qb, Kb, Vb);

    dim3 ga(10, 1024);            // q-tiles x (B*H)
    attn_fwd<<<ga, 256, 0, stream>>>(Qb, Kb, Vb, out);
}

// Round 5
// 673.128 us; speedup vs baseline: 1.3695x; 1.0850x over previous
//
#include <hip/hip_runtime.h>
#include <hip/hip_bf16.h>

// Problem: B=64, N=577, E=1024, H=16, D=64.
// out = softmax((xWq^T)(xWk^T)^T / 8) (xWv^T), head-split.
// ws: Q,K,V bf16 [B][H][N][D], 75,628,544 B each (226.9 MB total).
// d_out doubles as scratch for bf16 x + bf16 W concat; attn overwrites it.

typedef __attribute__((ext_vector_type(8))) short s16x8;
typedef __attribute__((ext_vector_type(4))) float f32x4;
typedef __attribute__((ext_vector_type(16))) float f32x16;
typedef __attribute__((ext_vector_type(4))) unsigned int u32x4;
typedef __attribute__((ext_vector_type(2))) unsigned int u32x2;

#define MFMA16(a, b, c) __builtin_amdgcn_mfma_f32_16x16x32_bf16((a), (b), (c), 0, 0, 0)
#define MFMA32(a, b, c) __builtin_amdgcn_mfma_f32_32x32x16_bf16((a), (b), (c), 0, 0, 0)

__device__ __forceinline__ short f2bf(float f) {
    unsigned u = __builtin_bit_cast(unsigned, f);
    u += 0x7FFFu + ((u >> 16) & 1u);   // round-to-nearest-even
    return (short)(u >> 16);
}

__device__ __forceinline__ unsigned cvtpk(float lo, float hi) {
    unsigned r;
    asm("v_cvt_pk_bf16_f32 %0, %1, %2" : "=v"(r) : "v"(lo), "v"(hi));
    return r;
}

__device__ __forceinline__ void gload_lds16(const void* g, void* l) {
    __builtin_amdgcn_global_load_lds(
        (const __attribute__((address_space(1))) unsigned int*)g,
        (__attribute__((address_space(3))) unsigned int*)l,
        16, 0, 0);
}

// ---------------------------------------------------------------------------
// Convert x (36928x1024 f32) and Wq|Wk|Wv (each 1024x1024 f32) to bf16.
// ---------------------------------------------------------------------------
__global__ __launch_bounds__(256) void convert_bf16(
    const float* __restrict__ x,
    const float* __restrict__ Wq,
    const float* __restrict__ Wk,
    const float* __restrict__ Wv,
    short* __restrict__ dst)
{
    constexpr size_t NX = 37814272u / 8u;
    constexpr size_t NW = 1048576u / 8u;
    constexpr size_t NTOT = NX + 3u * NW;
    size_t stride = (size_t)gridDim.x * blockDim.x;
    for (size_t c = (size_t)blockIdx.x * blockDim.x + threadIdx.x; c < NTOT; c += stride) {
        const float* src;
        size_t off;
        if (c < NX) { src = x; off = c * 8; }
        else {
            size_t cw = c - NX;
            int wsel = (int)(cw / NW);
            src = (wsel == 0) ? Wq : (wsel == 1) ? Wk : Wv;
            off = (cw - (size_t)wsel * NW) * 8;
        }
        float4 a0 = *reinterpret_cast<const float4*>(src + off);
        float4 a1 = *reinterpret_cast<const float4*>(src + off + 4);
        s16x8 v;
        v[0]=f2bf(a0.x); v[1]=f2bf(a0.y); v[2]=f2bf(a0.z); v[3]=f2bf(a0.w);
        v[4]=f2bf(a1.x); v[5]=f2bf(a1.y); v[6]=f2bf(a1.z); v[7]=f2bf(a1.w);
        *reinterpret_cast<s16x8*>(dst + c * 8) = v;
    }
}

// ---------------------------------------------------------------------------
// Fused QKV GEMM (m97 structure), unchanged from R2.
// ---------------------------------------------------------------------------
__global__ __launch_bounds__(256) void qkv_gemm2(
    const short* __restrict__ xb,
    const short* __restrict__ Wb,
    short* __restrict__ Qb,
    short* __restrict__ Kb,
    short* __restrict__ Vb)
{
    constexpr int M = 36928;
    constexpr int NTILES = 24;
    constexpr int NWG = 289 * NTILES;     // 6936 (div by 8)
    __shared__ short As[128 * 32];
    __shared__ short Bs[128 * 32];

    const int t    = threadIdx.x;
    const int lane = t & 63;
    const int w    = t >> 6;
    const int wr   = w >> 1, wc = w & 1;
    const int g    = lane >> 4, ml = lane & 15;

    int bid = blockIdx.x;
    int id  = (bid & 7) * (NWG / 8) + (bid >> 3);
    const int tileM = (id / NTILES) * 128;
    const int tileN = (id % NTILES) * 128;

    f32x4 acc[4][4] = {};
    const char* Abase = (const char*)xb;
    const char* Bbase = (const char*)Wb + (size_t)tileN * 2048;

    for (int k0 = 0; k0 < 1024; k0 += 32) {
        #pragma unroll
        for (int p = 0; p < 2; ++p) {
            int idx = p * 256 + t;
            int row = idx >> 2;
            int cb  = (idx & 3) * 16;
            int ar  = tileM + row; if (ar > M - 1) ar = M - 1;
            gload_lds16(Abase + (size_t)ar * 2048 + k0 * 2 + cb, (char*)As + idx * 16);
            gload_lds16(Bbase + (size_t)row * 2048 + k0 * 2 + cb, (char*)Bs + idx * 16);
        }
        __syncthreads();

        s16x8 af[4], bf8[4];
        #pragma unroll
        for (int i = 0; i < 4; ++i) {
            af[i]  = *reinterpret_cast<const s16x8*>(&As[(wr*64 + i*16 + ml) * 32 + g*8]);
            bf8[i] = *reinterpret_cast<const s16x8*>(&Bs[(wc*64 + i*16 + ml) * 32 + g*8]);
        }
        #pragma unroll
        for (int mi = 0; mi < 4; ++mi)
            #pragma unroll
            for (int ni = 0; ni < 4; ++ni)
                acc[mi][ni] = MFMA16(af[mi], bf8[ni], acc[mi][ni]);
        __syncthreads();
    }

    const int z = tileN >> 10;
    short* Ob = (z == 0) ? Qb : (z == 1) ? Kb : Vb;
    const int cbase = (tileN & 1023) + wc * 64;

    #pragma unroll
    for (int mi = 0; mi < 4; ++mi) {
        #pragma unroll
        for (int j = 0; j < 4; ++j) {
            int row = tileM + wr*64 + mi*16 + g*4 + j;
            if (row < M) {
                int b = row / 577;
                int n = row - b * 577;
                #pragma unroll
                for (int ni = 0; ni < 4; ++ni) {
                    int cz = cbase + ni*16 + ml;
                    int h = cz >> 6, dd = cz & 63;
                    Ob[(((size_t)(b * 16 + h)) * 577 + n) * 64 + dd] = f2bf(acc[mi][ni][j]);
                }
            }
        }
    }
}

// ---------------------------------------------------------------------------
// Flash attention v2: swapped 32x32 QK^T (S^T, lane = q-column), in-register
// softmax, cvt_pk+permlane32_swap P repack, O^T PV (lane = q-column).
// K/Q fragments straight from global; only V staged in LDS (swizzled transpose).
// Grid: 5120 1-D; swizzle puts the 5 q-blocks of each bh on one XCD, adjacent.
// ---------------------------------------------------------------------------
__global__ __launch_bounds__(256) void attn_fwd2(
    const short* __restrict__ Qb,
    const short* __restrict__ Kb,
    const short* __restrict__ Vb,
    float* __restrict__ out)
{
    constexpr int   N    = 577;
    constexpr float CEXP = 0.18033688011112042f;   // 0.125 * log2(e)

    __shared__ short VTs[64 * 72];   // [d][key^sw], sw = ((d>>3)&7)<<3

    const int t     = threadIdx.x;
    const int lane  = t & 63;
    const int w     = t >> 6;
    const int col_q = lane & 31;       // q (and d) column index
    const int hi    = lane >> 5;
    const int hi8   = hi * 8;

    // block swizzle: all 5 q-tiles of one bh adjacent + same XCD
    int bd  = blockIdx.x;              // 0..5119
    int x   = bd & 7;
    int r_  = bd >> 3;                 // 0..639
    int qt  = r_ % 5;
    int bh  = (r_ / 5) * 8 + x;
    const int bB = bh >> 4, hH = bh & 15;
    const size_t slab = (size_t)bh * (N * 64);

    const int q0 = qt * 128 + w * 32;

    // Q fragments: qb[ks] lane l = Q[q0+col_q][ks*16 + hi8 .. +7]
    s16x8 qb[4];
    {
        int qr = q0 + col_q; if (qr > N - 1) qr = N - 1;
        const short* qrow = Qb + slab + (size_t)qr * 64 + hi8;
        #pragma unroll
        for (int ks = 0; ks < 4; ++ks)
            qb[ks] = *reinterpret_cast<const s16x8*>(qrow + ks * 16);
    }

    float m_run = -1e30f, l_run = 0.f;
    f32x16 o0 = {}, o1 = {};

    for (int kv0 = 0; kv0 < N; kv0 += 64) {
        // ---- stage V transposed into LDS (swizzled) ----
        {
            int key  = t >> 2;
            int krow = kv0 + key; if (krow > N - 1) krow = N - 1;
            const short* gv = Vb + slab + (size_t)krow * 64;
            #pragma unroll
            for (int p = 0; p < 2; ++p) {
                int d0 = (t & 3) * 16 + p * 8;
                s16x8 vv = *reinterpret_cast<const s16x8*>(gv + d0);
                #pragma unroll
                for (int j = 0; j < 8; ++j) {
                    int dd = d0 + j;
                    VTs[dd * 72 + (key ^ (((dd >> 3) & 7) << 3))] = vv[j];
                }
            }
        }
        __syncthreads();

        // ---- S^T = K * Q^T : two 32-key blocks ----
        f32x16 s0 = {}, s1 = {};
        {
            const short* kr0 = Kb + slab + (size_t)(kv0 + col_q) * 64 + hi8;
            const short* kr1 = kr0 + (size_t)32 * 64;
            #pragma unroll
            for (int ks = 0; ks < 4; ++ks) {
                s16x8 kf0 = *reinterpret_cast<const s16x8*>(kr0 + ks * 16);
                s0 = MFMA32(kf0, qb[ks], s0);
            }
            #pragma unroll
            for (int ks = 0; ks < 4; ++ks) {
                s16x8 kf1 = *reinterpret_cast<const s16x8*>(kr1 + ks * 16);
                s1 = MFMA32(kf1, qb[ks], s1);
            }
        }

        // ---- mask tail keys (only last tile: kv0 = 576) ----
        if (kv0 + 64 > N) {
            #pragma unroll
            for (int r = 0; r < 16; ++r) {
                int crow = (r & 3) + 8 * (r >> 2) + 4 * hi;
                if (kv0 + crow > N - 1) s0[r] = -1e30f;
                s1[r] = -1e30f;
            }
        }

        // ---- online softmax (per-lane: own q-column, 32 of 64 keys) ----
        float pm = s0[0];
        #pragma unroll
        for (int r = 1; r < 16; ++r) pm = fmaxf(pm, s0[r]);
        #pragma unroll
        for (int r = 0; r < 16; ++r) pm = fmaxf(pm, s1[r]);
        float tm = fmaxf(pm, __shfl_xor(pm, 32));
        float mn = fmaxf(m_run, tm);
        float corr = exp2f(CEXP * (m_run - mn));
        float cmn = CEXP * mn;
        m_run = mn;

        float psum = 0.f;
        #pragma unroll
        for (int r = 0; r < 16; ++r) { s0[r] = exp2f(s0[r] * CEXP - cmn); psum += s0[r]; }
        #pragma unroll
        for (int r = 0; r < 16; ++r) { s1[r] = exp2f(s1[r] * CEXP - cmn); psum += s1[r]; }
        psum += __shfl_xor(psum, 32);
        l_run = l_run * corr + psum;

        #pragma unroll
        for (int r = 0; r < 16; ++r) { o0[r] *= corr; o1[r] *= corr; }

        // ---- repack P to bf16 A/B fragments: pw[4] over key slices of 16 ----
        u32x4 pw[4];
        {
            u32x2 rr;
            rr = __builtin_amdgcn_permlane32_swap(cvtpk(s0[0], s0[1]),  cvtpk(s0[4], s0[5]),  false, false);
            pw[0][0] = rr[0]; pw[0][2] = rr[1];
            rr = __builtin_amdgcn_permlane32_swap(cvtpk(s0[2], s0[3]),  cvtpk(s0[6], s0[7]),  false, false);
            pw[0][1] = rr[0]; pw[0][3] = rr[1];
            rr = __builtin_amdgcn_permlane32_swap(cvtpk(s0[8], s0[9]),  cvtpk(s0[12], s0[13]), false, false);
            pw[1][0] = rr[0]; pw[1][2] = rr[1];
            rr = __builtin_amdgcn_permlane32_swap(cvtpk(s0[10], s0[11]), cvtpk(s0[14], s0[15]), false, false);
            pw[1][1] = rr[0]; pw[1][3] = rr[1];
            rr = __builtin_amdgcn_permlane32_swap(cvtpk(s1[0], s1[1]),  cvtpk(s1[4], s1[5]),  false, false);
            pw[2][0] = rr[0]; pw[2][2] = rr[1];
            rr = __builtin_amdgcn_permlane32_swap(cvtpk(s1[2], s1[3]),  cvtpk(s1[6], s1[7]),  false, false);
            pw[2][1] = rr[0]; pw[2][3] = rr[1];
            rr = __builtin_amdgcn_permlane32_swap(cvtpk(s1[8], s1[9]),  cvtpk(s1[12], s1[13]), false, false);
            pw[3][0] = rr[0]; pw[3][2] = rr[1];
            rr = __builtin_amdgcn_permlane32_swap(cvtpk(s1[10], s1[11]), cvtpk(s1[14], s1[15]), false, false);
            pw[3][1] = rr[0]; pw[3][3] = rr[1];
        }

        // ---- O^T += V^T * P : lane = q-column, rows = d ----
        {
            const int d_lo = col_q;            // dblk 0
            const int sw_lo = ((d_lo >> 3) & 7) << 3;
            const short* vr0 = &VTs[d_lo * 72];
            const int d_hi2 = 32 + col_q;      // dblk 1
            const int sw_hi = ((d_hi2 >> 3) & 7) << 3;
            const short* vr1 = &VTs[d_hi2 * 72];
            #pragma unroll
            for (int ks = 0; ks < 4; ++ks) {
                s16x8 paf = __builtin_bit_cast(s16x8, pw[ks]);
                s16x8 vf0 = *reinterpret_cast<const s16x8*>(vr0 + ((ks * 16 + hi8) ^ sw_lo));
                o0 = MFMA32(vf0, paf, o0);
                s16x8 vf1 = *reinterpret_cast<const s16x8*>(vr1 + ((ks * 16 + hi8) ^ sw_hi));
                o1 = MFMA32(vf1, paf, o1);
            }
        }
        __syncthreads();   // VT reads done before next stage
    }

    // ---- epilogue: out[b, q, h*64 + d], d = dblk*32 + 8*gq + 4*hi + e ----
    int q = q0 + col_q;
    if (q < N) {
        float inv = 1.0f / l_run;
        float* obase = out + ((size_t)bB * 577 + q) * 1024 + (size_t)hH * 64;
        #pragma unroll
        for (int gq = 0; gq < 4; ++gq) {
            float4 v0 = { o0[4*gq+0]*inv, o0[4*gq+1]*inv, o0[4*gq+2]*inv, o0[4*gq+3]*inv };
            *reinterpret_cast<float4*>(obase + 8*gq + 4*hi) = v0;
            float4 v1 = { o1[4*gq+0]*inv, o1[4*gq+1]*inv, o1[4*gq+2]*inv, o1[4*gq+3]*inv };
            *reinterpret_cast<float4*>(obase + 32 + 8*gq + 4*hi) = v1;
        }
    }
}

extern "C" void kernel_launch(void* const* d_in, const int* in_sizes, int n_in,
                              void* d_out, int out_size, void* d_ws, size_t ws_size,
                              hipStream_t stream) {
    const float* x  = (const float*)d_in[0];
    const float* Wq = (const float*)d_in[1];
    const float* Wk = (const float*)d_in[2];
    const float* Wv = (const float*)d_in[3];
    float* out = (float*)d_out;

    const size_t SZ = (size_t)64 * 16 * 577 * 64 * 2;   // 75,628,544 B per tensor
    short* Qb = (short*)d_ws;
    short* Kb = (short*)((char*)d_ws + SZ);
    short* Vb = (short*)((char*)d_ws + 2 * SZ);

    short* xb = (short*)d_out;                     // bf16 scratch in d_out
    short* Wb = xb + (size_t)37814272;

    convert_bf16<<<2048, 256, 0, stream>>>(x, Wq, Wk, Wv, xb);
    qkv_gemm2<<<dim3(289 * 24), 256, 0, stream>>>(xb, Wb, Qb, Kb, Vb);
    attn_fwd2<<<5120, 256, 0, stream>>>(Qb, Kb, Vb, out);
}